// Round 1
// baseline (311.719 us; speedup 1.0000x reference)
//
#include <hip/hip_runtime.h>

// RNN_33603824123977: per-timestep MLP with recurrent scalar feedback.
//   for t in 0..29: h = relu([x_t, o] @ W1[t] + b1[t]); o = tanh(h @ W2[t] + b2[t])
// One thread handles M=4 batch elements (2 float2 pairs for v_pk_fma_f32 packing).
// Weights (30*81 floats) staged in LDS as interleaved float4 {w1x, w1h, b1, w2}
// so each hidden unit j costs exactly one ds_read_b128 (broadcast, conflict-free).
// x rows live in registers across the fully-unrolled t-loop (exactly-once HBM
// traffic), outputs overwrite the same registers and are stored at the end.

#define TS  30
#define HID 20

typedef float f2 __attribute__((ext_vector_type(2)));

__device__ __forceinline__ float fast_tanh(float y) {
    // tanh(y) = 1 - 2/(exp(2y)+1); exp->inf => 1, exp->0 => -1 (safe at extremes)
    float e = __expf(2.0f * y);
    return 1.0f - 2.0f * __builtin_amdgcn_rcpf(e + 1.0f);
}

__global__ __launch_bounds__(256) void rnn_fused(
        const float* __restrict__ x,    // [B, 30, 1]
        const float* __restrict__ W1,   // [30, 2, 20]
        const float* __restrict__ b1,   // [30, 20]
        const float* __restrict__ W2,   // [30, 20, 1]
        const float* __restrict__ b2,   // [30, 1]
        float* __restrict__ out) {      // [B, 30, 1]
    __shared__ float4 wt[TS * HID];     // {W1[t][0][j], W1[t][1][j], b1[t][j], W2[t][j]}
    __shared__ float  wb2[TS];

    const int tid = threadIdx.x;
    for (int i = tid; i < TS * HID; i += 256) {
        const int t = i / HID;
        const int j = i - t * HID;
        wt[i] = make_float4(W1[t * 40 + j], W1[t * 40 + 20 + j],
                            b1[t * 20 + j], W2[t * 20 + j]);
    }
    if (tid < TS) wb2[tid] = b2[tid];
    __syncthreads();

    // 4 elements per thread: lanes adjacent -> rows adjacent in memory.
    const size_t e0 = (size_t)blockIdx.x * 1024 + (size_t)tid;
    const size_t e1 = e0 + 256;
    const size_t e2 = e0 + 512;
    const size_t e3 = e0 + 768;

    // Preload x rows (30 floats = 120 B each; 8B-aligned -> float2 loads).
    float r0[TS], r1[TS], r2[TS], r3[TS];
    {
        const float2* p0 = reinterpret_cast<const float2*>(x + e0 * TS);
        const float2* p1 = reinterpret_cast<const float2*>(x + e1 * TS);
        const float2* p2 = reinterpret_cast<const float2*>(x + e2 * TS);
        const float2* p3 = reinterpret_cast<const float2*>(x + e3 * TS);
#pragma unroll
        for (int i = 0; i < TS / 2; ++i) {
            float2 v;
            v = p0[i]; r0[2 * i] = v.x; r0[2 * i + 1] = v.y;
            v = p1[i]; r1[2 * i] = v.x; r1[2 * i + 1] = v.y;
            v = p2[i]; r2[2 * i] = v.x; r2[2 * i + 1] = v.y;
            v = p3[i]; r3[2 * i] = v.x; r3[2 * i + 1] = v.y;
        }
    }

    f2 oA = {0.0f, 0.0f};   // recurrent outputs, h0 = 0
    f2 oB = {0.0f, 0.0f};

#pragma unroll
    for (int t = 0; t < TS; ++t) {
        const float4* wrow = &wt[t * HID];
        const f2 xA = {r0[t], r1[t]};
        const f2 xB = {r2[t], r3[t]};
        const float bb = wb2[t];
        f2 accA = {bb, bb};
        f2 accB = {bb, bb};
#pragma unroll 4
        for (int j = 0; j < HID; ++j) {
            const float4 w = wrow[j];           // one ds_read_b128, broadcast
            f2 hA = xA * w.x + oA * w.y + w.z;  // contracts to (pk_)fma
            f2 hB = xB * w.x + oB * w.y + w.z;
            hA.x = __builtin_fmaxf(hA.x, 0.0f);
            hA.y = __builtin_fmaxf(hA.y, 0.0f);
            hB.x = __builtin_fmaxf(hB.x, 0.0f);
            hB.y = __builtin_fmaxf(hB.y, 0.0f);
            accA += hA * w.w;
            accB += hB * w.w;
        }
        oA.x = fast_tanh(accA.x);
        oA.y = fast_tanh(accA.y);
        oB.x = fast_tanh(accB.x);
        oB.y = fast_tanh(accB.y);
        r0[t] = oA.x; r1[t] = oA.y; r2[t] = oB.x; r3[t] = oB.y;
    }

    // Write rows back (float2 stores, 8B-aligned).
    {
        float2* q0 = reinterpret_cast<float2*>(out + e0 * TS);
        float2* q1 = reinterpret_cast<float2*>(out + e1 * TS);
        float2* q2 = reinterpret_cast<float2*>(out + e2 * TS);
        float2* q3 = reinterpret_cast<float2*>(out + e3 * TS);
#pragma unroll
        for (int i = 0; i < TS / 2; ++i) {
            q0[i] = make_float2(r0[2 * i], r0[2 * i + 1]);
            q1[i] = make_float2(r1[2 * i], r1[2 * i + 1]);
            q2[i] = make_float2(r2[2 * i], r2[2 * i + 1]);
            q3[i] = make_float2(r3[2 * i], r3[2 * i + 1]);
        }
    }
}

extern "C" void kernel_launch(void* const* d_in, const int* in_sizes, int n_in,
                              void* d_out, int out_size, void* d_ws, size_t ws_size,
                              hipStream_t stream) {
    const float* x  = (const float*)d_in[0];
    const float* W1 = (const float*)d_in[1];
    const float* b1 = (const float*)d_in[2];
    const float* W2 = (const float*)d_in[3];
    const float* b2 = (const float*)d_in[4];
    float* out = (float*)d_out;

    const int B = 1048576;
    const int elems_per_block = 256 * 4;            // 256 threads * M=4
    const int grid = B / elems_per_block;           // 1024 blocks
    rnn_fused<<<grid, 256, 0, stream>>>(x, W1, b1, W2, b2, out);
}

// Round 2
// 266.626 us; speedup vs baseline: 1.1691x; 1.1691x over previous
//
#include <hip/hip_runtime.h>

// RNN: o_t = tanh(relu([x_t, o_{t-1}] @ W1[t] + b1[t]) @ W2[t] + b2[t]), T=30.
// Round-2 design:
//  - Weights repacked (kernel 1) into d_ws as float4 {w1x, w1h, b1, w2}[t][j]
//    (+ slot j=20 carrying b2[t]). In the main kernel these are read with
//    wave-UNIFORM indices through const __restrict__ -> compiler emits s_load
//    (scalar pipe), removing ~48us of LDS ds_read_b128 traffic from round 1.
//  - Global I/O fully coalesced float4 via an LDS transpose tile [30][514]
//    (pad 514 keeps b64 compute reads 8B-aligned and scatter aliasing 2-way,
//    which is free). Tile is overwritten in place: slot [t][e] holds x before
//    step t and o after it -> one 61.7KB tile serves input AND output.
//  - M=2 elems/thread as a float2 ext-vector -> v_pk_fma_f32 packing.
// Occupancy: LDS-capped at 2 blocks/CU (8 waves/CU). Memory floor 40us,
// VALU floor ~22us.

#define TS  30
#define HID 20
#define THR 256
#define EPB 512              // elements per block (M=2)
#define ROW 514              // LDS row stride in floats (even + conflict-safe)

typedef float f2 __attribute__((ext_vector_type(2)));

__device__ __forceinline__ float fast_tanh(float y) {
    // tanh(y) = 1 - 2/(exp(2y)+1); correct saturation at +/-inf.
    float e = __expf(2.0f * y);
    return 1.0f - 2.0f * __builtin_amdgcn_rcpf(e + 1.0f);
}

__global__ __launch_bounds__(256) void repack_w(
        const float* __restrict__ W1, const float* __restrict__ b1,
        const float* __restrict__ W2, const float* __restrict__ b2,
        float4* __restrict__ wp) {
    for (int i = threadIdx.x; i < TS * 21; i += 256) {
        const int t = i / 21;
        const int j = i - t * 21;
        float4 v;
        if (j < HID) v = make_float4(W1[t * 40 + j], W1[t * 40 + 20 + j],
                                     b1[t * 20 + j], W2[t * 20 + j]);
        else         v = make_float4(b2[t], 0.f, 0.f, 0.f);
        wp[i] = v;
    }
}

__global__ __launch_bounds__(256) void rnn2(
        const float* __restrict__ x,
        const float4* __restrict__ wp,
        float* __restrict__ out) {
    __shared__ float tile[TS * ROW];
    const int tid = threadIdx.x;
    const size_t gbase = (size_t)blockIdx.x * (EPB * TS);

    // ---- coalesced load + LDS transpose scatter ----
    const float4* xg = reinterpret_cast<const float4*>(x + gbase);
#pragma unroll
    for (int i = 0; i < 15; ++i) {
        float4 v = xg[i * THR + tid];
        const unsigned fo = (unsigned)(i * THR + tid) * 4u;
        const float* vp = reinterpret_cast<const float*>(&v);
#pragma unroll
        for (int k = 0; k < 4; ++k) {
            const unsigned f = fo + k;
            const unsigned e = (f * 34953u) >> 20;   // exact f/30 for f < 74898
            const unsigned t = f - e * 30u;
            tile[t * ROW + e] = vp[k];
        }
    }
    __syncthreads();

    // ---- recurrence: M=2 elems per thread, weights via scalar loads ----
    f2 o = {0.f, 0.f};
    const int e0 = 2 * tid;
#pragma unroll 1
    for (int t = 0; t < TS; ++t) {
        const float4* wr = wp + t * 21;              // wave-uniform -> s_load
        const f2 xv = *reinterpret_cast<const f2*>(&tile[t * ROW + e0]);
        const float bb = wr[20].x;
        f2 acc = {bb, bb};
#pragma unroll
        for (int j = 0; j < HID; ++j) {
            const float4 w = wr[j];                  // s_load_dwordx4
            f2 h = xv * w.x + o * w.y + w.z;         // 2x v_pk_fma_f32
            h.x = __builtin_fmaxf(h.x, 0.f);
            h.y = __builtin_fmaxf(h.y, 0.f);
            acc += h * w.w;                          // v_pk_fma_f32
        }
        o.x = fast_tanh(acc.x);
        o.y = fast_tanh(acc.y);
        *reinterpret_cast<f2*>(&tile[t * ROW + e0]) = o;  // in-place: x -> o
    }
    __syncthreads();

    // ---- LDS gather + coalesced store ----
    float4* og = reinterpret_cast<float4*>(out + gbase);
#pragma unroll
    for (int i = 0; i < 15; ++i) {
        const unsigned fo = (unsigned)(i * THR + tid) * 4u;
        float4 v;
        float* vp = reinterpret_cast<float*>(&v);
#pragma unroll
        for (int k = 0; k < 4; ++k) {
            const unsigned f = fo + k;
            const unsigned e = (f * 34953u) >> 20;
            const unsigned t = f - e * 30u;
            vp[k] = tile[t * ROW + e];
        }
        og[i * THR + tid] = v;
    }
}

extern "C" void kernel_launch(void* const* d_in, const int* in_sizes, int n_in,
                              void* d_out, int out_size, void* d_ws, size_t ws_size,
                              hipStream_t stream) {
    const float* x  = (const float*)d_in[0];
    const float* W1 = (const float*)d_in[1];
    const float* b1 = (const float*)d_in[2];
    const float* W2 = (const float*)d_in[3];
    const float* b2 = (const float*)d_in[4];
    float* out = (float*)d_out;
    float4* wp = (float4*)d_ws;                      // 30*21*16 = 10080 B

    repack_w<<<1, 256, 0, stream>>>(W1, b1, W2, b2, wp);

    const int B = 1048576;
    const int grid = B / EPB;                        // 2048 blocks
    rnn2<<<grid, 256, 0, stream>>>(x, wp, out);
}